// Round 6
// baseline (183.543 us; speedup 1.0000x reference)
//
#include <hip/hip_runtime.h>
#include <cstdint>

#define BATCH 16
#define SEQ 2048
#define EMB 512
#define FFN 2048
#define NQ 8
#define M_TOTAL (BATCH * SEQ)   // 32768

#define BM 128
#define BN 128
#define BK 64
#define NTHREADS 256            // 4 waves: 2 (m) x 2 (n), wave tile 64x64

typedef __attribute__((ext_vector_type(8))) short short8;   // 8 bf16 (MFMA A/B frag)
typedef __attribute__((ext_vector_type(4))) float float4v;  // MFMA C/D frag
typedef __attribute__((ext_vector_type(4))) unsigned int uint4v;

// fp32 -> bf16 bits, round-to-nearest-even (finite inputs) — prep kernels only
static __device__ __forceinline__ unsigned int f2bf(float f) {
    unsigned int u = __builtin_bit_cast(unsigned int, f);
    return (u + 0x7fffu + ((u >> 16) & 1u)) >> 16;
}
static __device__ __forceinline__ unsigned int f2bf_pk(float lo, float hi) {
    return f2bf(lo) | (f2bf(hi) << 16);
}
// single-instruction RTNE pack (hot path)
static __device__ __forceinline__ unsigned int cvt_pk_bf16(float lo, float hi) {
    unsigned int r;
    asm("v_cvt_pk_bf16_f32 %0, %1, %2" : "=v"(r) : "v"(lo), "v"(hi));
    return r;
}

// ---- prep: fp32 -> bf16 pairs (used for W2 [EMB][FFN] and W1 [FFN][NQ]) ----
__global__ __launch_bounds__(256) void prep_w2(const float* __restrict__ W2,
                                               unsigned int* __restrict__ w2b) {
    int idx = (blockIdx.x * 256 + threadIdx.x) * 4;
    float4 v = *(const float4*)&W2[idx];
    w2b[idx / 2]     = f2bf_pk(v.x, v.y);
    w2b[idx / 2 + 1] = f2bf_pk(v.z, v.w);
}

// v7: BK=64 -> 32 K-steps (was 64). R1/R4/R5 showed a fixed ~1600-cyc/step
// overhead (barrier + latency chain) insensitive to traffic/VALU/waves; the
// per-SIMD MFMA demand is ~1400 cyc/step in every geometry. Halving the step
// count halves the total overhead. Schedule = R4's (1 __syncthreads/step,
// double buffer, stage+W1-load first, compute, hgen last).
//
// LDS tile layout for BK=64: row stride 64 bf16 = 128 B = 8 chunks of 16 B.
// Logical k-chunk q of row r lives at physical chunk q ^ (r&7): a frag read
// (16 rows x one quad per phase) covers 8 chunk-slots x 2 rows = 2-way = free.

__global__ __launch_bounds__(NTHREADS, 2) void ffq_main(
    const float* __restrict__ x,              // [M_TOTAL][EMB], cols 0..7 used
    const float* __restrict__ theta,          // [8]
    const unsigned short* __restrict__ w1b,   // [FFN][NQ] bf16 bits
    const unsigned short* __restrict__ w2b,   // [EMB][FFN] bf16 bits
    float* __restrict__ out)                  // [M_TOTAL][EMB]
{
    __shared__ unsigned short Asm[2][BM * BK];   // 2 x 16 KB  h tile, swizzled
    __shared__ unsigned short Bsm[2][BN * BK];   // 2 x 16 KB  W2 tile, swizzled
    // total 64 KB -> 2 blocks/CU

    const int t    = threadIdx.x;
    const int m0   = blockIdx.x * BM;
    const int n0   = blockIdx.y * BN;
    const int wave = t >> 6, lane = t & 63;
    const int quad = lane >> 4, l16 = lane & 15;
    const int wm   = wave >> 1, wn = wave & 1;   // wave tile: m wm*64.., n wn*64..
    const int rsw  = l16 & 7;                    // row&7 for all frag rows

    // ---- per-wave persistent Q fragments (B-operand of h-gen MFMA) ----
    // 4 waves produce all BM=128 h rows -> 32 rows/wave (g2 = 0,1).
    short8 qfrag[2];
#pragma unroll
    for (int g2 = 0; g2 < 2; ++g2) {
        int qrow = m0 + wave * 32 + g2 * 16 + l16;
        const float* xr = x + (size_t)qrow * EMB;
        float4 xa = *(const float4*)xr;
        float4 xb = *(const float4*)(xr + 4);
        uint4v uq;
        uq[0] = f2bf_pk(__cosf(2.f * xa.x + theta[0]), __cosf(2.f * xa.y + theta[1]));
        uq[1] = f2bf_pk(__cosf(2.f * xa.z + theta[2]), __cosf(2.f * xa.w + theta[3]));
        uq[2] = f2bf_pk(__cosf(2.f * xb.x + theta[4]), __cosf(2.f * xb.y + theta[5]));
        uq[3] = f2bf_pk(__cosf(2.f * xb.z + theta[6]), __cosf(2.f * xb.w + theta[7]));
        qfrag[g2] = __builtin_bit_cast(short8, uq);
        if (quad != 0) qfrag[g2] = (short8)0;
    }

    // ---- per-thread B-staging constants (chunk -> source-swizzled gaddr) ----
    // B tile = BN*8 = 1024 chunks of 16 B; 256 threads -> 4 chunks each.
    const unsigned short* gB[4];
#pragma unroll
    for (int i = 0; i < 4; ++i) {
        int c = i * NTHREADS + t;
        int n = c >> 3, s = c & 7;
        int qk = s ^ (n & 7);                     // logical k-chunk at phys slot s
        gB[i] = w2b + (size_t)(n0 + n) * FFN + qk * 8;
    }

    auto stageB = [&](int k0, int buf) __attribute__((always_inline)) {
#pragma unroll
        for (int i = 0; i < 4; ++i) {
            int c = i * NTHREADS + t;
            __builtin_amdgcn_global_load_lds(
                (const __attribute__((address_space(1))) unsigned int*)(gB[i] + k0),
                (__attribute__((address_space(3))) unsigned int*)(uintptr_t)(&Bsm[buf][c * 8]),
                16, 0, 0);
        }
    };

    // W1 fragment loads for K-rows [kh, kh+64): 16 B/lane, L1/L2-resident
    auto loadW1 = [&](int kh, short8* w1f) __attribute__((always_inline)) {
#pragma unroll
        for (int fh = 0; fh < 4; ++fh)
            w1f[fh] = *(const short8*)&w1b[(size_t)(kh + fh * 16 + l16) * NQ];
    };

    // h-gen via MFMA from register W1 frags, relu, cvt_pk -> swizzled Asm[buf]
    // D: row quad*4+r -> kcol fh*16+quad*4+r, col l16 -> m. One 8-B write per MFMA.
    auto hgen = [&](int buf, const short8* w1f) __attribute__((always_inline)) {
#pragma unroll
        for (int g2 = 0; g2 < 2; ++g2) {
            int m = wave * 32 + g2 * 16 + l16;
#pragma unroll
            for (int fh = 0; fh < 4; ++fh) {
                float4v hc = __builtin_amdgcn_mfma_f32_16x16x32_bf16(
                    w1f[fh], qfrag[g2], (float4v)0.0f, 0, 0, 0);
                unsigned int p0 = cvt_pk_bf16(fmaxf(hc[0], 0.f), fmaxf(hc[1], 0.f));
                unsigned int p1 = cvt_pk_bf16(fmaxf(hc[2], 0.f), fmaxf(hc[3], 0.f));
                int qph = (fh * 2 + (quad >> 1)) ^ rsw;   // chunk of kcol fh*16+quad*4
                unsigned long long pk = ((unsigned long long)p1 << 32) | p0;
                *(unsigned long long*)&Asm[buf][m * BK + qph * 8 + (quad & 1) * 4] = pk;
            }
        }
    };

    float4v acc[16];
#pragma unroll
    for (int i = 0; i < 16; ++i) acc[i] = (float4v)0.0f;

    // conflict-free fragment loads + 32 MFMA (2 K-halves) from buffers [buf]
    auto compute = [&](int buf) __attribute__((always_inline)) {
#pragma unroll
        for (int kk = 0; kk < 2; ++kk) {
            short8 af[4], bfr[4];
#pragma unroll
            for (int fm = 0; fm < 4; ++fm) {
                int row = wm * 64 + fm * 16 + l16;
                int qph = (kk * 4 + quad) ^ rsw;
                af[fm] = *(const short8*)&Asm[buf][row * BK + qph * 8];
            }
#pragma unroll
            for (int fn = 0; fn < 4; ++fn) {
                int row = wn * 64 + fn * 16 + l16;
                int qph = (kk * 4 + quad) ^ rsw;
                bfr[fn] = *(const short8*)&Bsm[buf][row * BK + qph * 8];
            }
            __builtin_amdgcn_s_setprio(1);
#pragma unroll
            for (int fm = 0; fm < 4; ++fm)
#pragma unroll
                for (int fn = 0; fn < 4; ++fn)
                    acc[fm * 4 + fn] = __builtin_amdgcn_mfma_f32_16x16x32_bf16(
                        af[fm], bfr[fn], acc[fm * 4 + fn], 0, 0, 0);
            __builtin_amdgcn_s_setprio(0);
        }
    };

    // ---- prologue: tile 0 ----
    {
        short8 w1f[4];
        loadW1(0, w1f);
        stageB(0, 0);
        hgen(0, w1f);
    }
    __syncthreads();        // vmcnt: B(0) landed; lgkm: h(0) visible

    // ---- pipelined main loop: 32 K-steps, 1 barrier each ----
    // pair-unrolled so the buffer parity is a compile-time constant
    for (int kt = 0; kt < 30; kt += 2) {
        {   // step kt (cb=0): produce tile kt+1
            short8 w1f[4];
            loadW1((kt + 1) * BK, w1f);
            stageB((kt + 1) * BK, 1);
            compute(0);
            hgen(1, w1f);
        }
        __syncthreads();
        {   // step kt+1 (cb=1): produce tile kt+2
            short8 w1f[4];
            loadW1((kt + 2) * BK, w1f);
            stageB((kt + 2) * BK, 0);
            compute(1);
            hgen(0, w1f);
        }
        __syncthreads();
    }
    // kt = 30 (cb=0): produce last tile (31)
    {
        short8 w1f[4];
        loadW1(31 * BK, w1f);
        stageB(31 * BK, 1);
        compute(0);
        hgen(1, w1f);
    }
    __syncthreads();
    // kt = 31: tail, compute only
    compute(1);

    // ---- epilogue: D layout col=lane&15 (n), row=quad*4+reg (m) ----
    const int om = m0 + wm * 64;
    const int on = n0 + wn * 64;
#pragma unroll
    for (int fm = 0; fm < 4; ++fm) {
#pragma unroll
        for (int fn = 0; fn < 4; ++fn) {
            float4v v = acc[fm * 4 + fn];
            int rbase = om + fm * 16 + quad * 4;
            int c     = on + fn * 16 + l16;
#pragma unroll
            for (int r = 0; r < 4; ++r)
                out[(size_t)(rbase + r) * EMB + c] = v[r];
        }
    }
}

extern "C" void kernel_launch(void* const* d_in, const int* in_sizes, int n_in,
                              void* d_out, int out_size, void* d_ws, size_t ws_size,
                              hipStream_t stream) {
    const float* x     = (const float*)d_in[0];
    const float* theta = (const float*)d_in[1];
    const float* W1    = (const float*)d_in[2];
    const float* W2    = (const float*)d_in[3];
    float* out = (float*)d_out;

    unsigned int* w2b = (unsigned int*)d_ws;               // 2 MiB (bf16 bits)
    unsigned int* w1b = (unsigned int*)((char*)d_ws + (size_t)EMB * FFN * 2);  // 32 KB

    prep_w2<<<(EMB * FFN) / (256 * 4), 256, 0, stream>>>(W2, w2b);
    prep_w2<<<(FFN * NQ) / (256 * 4), 256, 0, stream>>>(W1, w1b);   // 16 blocks

    dim3 grid(M_TOTAL / BM, EMB / BN);         // 256 x 4 = 1024 blocks, 2/CU
    ffq_main<<<grid, NTHREADS, 0, stream>>>(x, theta,
                                            (const unsigned short*)w1b,
                                            (const unsigned short*)w2b, out);
}

// Round 7
// 182.113 us; speedup vs baseline: 1.0079x; 1.0079x over previous
//
#include <hip/hip_runtime.h>
#include <cstdint>

#define BATCH 16
#define SEQ 2048
#define EMB 512
#define FFN 2048
#define NQ 8
#define M_TOTAL (BATCH * SEQ)   // 32768

#define BM 128
#define BN 256
#define BK 32
#define NTHREADS 256            // 4 waves: 2 (m) x 2 (n), wave tile 64 x 128

typedef __attribute__((ext_vector_type(8))) short short8;      // 8 bf16 (MFMA A/B frag)
typedef __attribute__((ext_vector_type(16))) float float16v;   // 32x32 MFMA C/D frag
typedef __attribute__((ext_vector_type(4))) unsigned int uint4v;

// fp32 -> bf16 bits, round-to-nearest-even (finite inputs) — prep kernels only
static __device__ __forceinline__ unsigned int f2bf(float f) {
    unsigned int u = __builtin_bit_cast(unsigned int, f);
    return (u + 0x7fffu + ((u >> 16) & 1u)) >> 16;
}
static __device__ __forceinline__ unsigned int f2bf_pk(float lo, float hi) {
    return f2bf(lo) | (f2bf(hi) << 16);
}
// single-instruction RTNE pack (hot path)
static __device__ __forceinline__ unsigned int cvt_pk_bf16(float lo, float hi) {
    unsigned int r;
    asm("v_cvt_pk_bf16_f32 %0, %1, %2" : "=v"(r) : "v"(lo), "v"(hi));
    return r;
}

// ---- prep: W2 fp32 -> bf16 (row-major [EMB][FFN], K-contiguous) ----
__global__ __launch_bounds__(256) void prep_w2(const float* __restrict__ W2,
                                               unsigned int* __restrict__ w2b) {
    int idx = (blockIdx.x * 256 + threadIdx.x) * 4;
    float4 v = *(const float4*)&W2[idx];
    w2b[idx / 2]     = f2bf_pk(v.x, v.y);
    w2b[idx / 2 + 1] = f2bf_pk(v.z, v.w);
}

// ---- prep: W1 fp32 -> bf16, f-rows sigma-permuted within each 32-row tile ----
// sigma makes hgen's 32x32x16 D-layout (slot s = (reg&3)+8*(reg>>2)+4*hi)
// deliver h[f] exactly in main-MFMA A-operand order (k-slot = 8*hi + j):
// slot group g = s>>2: offset {0,+4,-4,0, 0,+4,-4,0}[g].
__global__ __launch_bounds__(256) void prep_w1(const float* __restrict__ W1,
                                               unsigned int* __restrict__ w1p) {
    int row = blockIdx.x * 256 + threadIdx.x;    // 2048 rows
    int g = (row >> 2) & 7;
    int off = ((g & 3) == 1) ? 4 : ((g & 3) == 2) ? -4 : 0;
    const float* s = &W1[(row + off) * NQ];
    float4 a = *(const float4*)s;
    float4 b = *(const float4*)(s + 4);
    w1p[row * 4 + 0] = f2bf_pk(a.x, a.y);
    w1p[row * 4 + 1] = f2bf_pk(a.z, a.w);
    w1p[row * 4 + 2] = f2bf_pk(b.x, b.y);
    w1p[row * 4 + 3] = f2bf_pk(b.z, b.w);
}

// v8: LDS-free A-path. h is generated per wave, per K-step, DIRECTLY into the
// main MFMA's A-fragments via one 32x32x16 MFMA per 32-m subtile (sigma-
// permuted W1 makes the D->A layouts line up; relu+cvt_pk are the only
// fix-up). Asm buffers, h ds_writes, af ds_reads and their barrier coupling
// are gone; the single __syncthreads per K-step guards only the DMA-staged
// Bsm (32 KB LDS total). Main GEMM also 32x32x16 (17% cheaper per FLOP).
//
// Bsm layout unchanged from R4/R5 (proven): row stride 32 bf16 = 4 chunks of
// 16 B, physical chunk = logical ^ ((row>>1)&3), source-swizzled DMA.
// bfr reads (32 rows x chunk kk*2+hi): slots (4*(row&1) + phys) cover 0..7
// per 8-lane phase -> conflict-free.

__global__ __launch_bounds__(NTHREADS, 2) void ffq_main(
    const float* __restrict__ x,              // [M_TOTAL][EMB], cols 0..7 used
    const float* __restrict__ theta,          // [8]
    const unsigned short* __restrict__ w1p,   // [FFN][8] bf16, sigma-permuted
    const unsigned short* __restrict__ w2b,   // [EMB][FFN] bf16 bits
    float* __restrict__ out)                  // [M_TOTAL][EMB]
{
    __shared__ unsigned short Bsm[2][BN * BK];   // 2 x 16 KB W2 tile, swizzled

    const int t    = threadIdx.x;
    const int m0   = blockIdx.x * BM;
    const int n0   = blockIdx.y * BN;
    const int wave = t >> 6, lane = t & 63;
    const int l32  = lane & 31, hi = lane >> 5;
    const int wm   = wave >> 1, wn = wave & 1;   // wave tile: m wm*64.., n wn*128..

    // ---- per-wave persistent Q fragments (B-operand of h-gen MFMA) ----
    // B layout (K16 x 32m): col = l32 -> m, k = hi*8+j. hi=0 lanes carry the
    // 8 angles; hi=1 lanes (k=8..15 padding) are zero (w1f hi half is also 0).
    short8 qfrag[2];
#pragma unroll
    for (int mh = 0; mh < 2; ++mh) {
        int qrow = m0 + wm * 64 + mh * 32 + l32;
        const float* xr = x + (size_t)qrow * EMB;
        float4 xa = *(const float4*)xr;
        float4 xb = *(const float4*)(xr + 4);
        uint4v uq;
        uq[0] = f2bf_pk(__cosf(2.f * xa.x + theta[0]), __cosf(2.f * xa.y + theta[1]));
        uq[1] = f2bf_pk(__cosf(2.f * xa.z + theta[2]), __cosf(2.f * xa.w + theta[3]));
        uq[2] = f2bf_pk(__cosf(2.f * xb.x + theta[4]), __cosf(2.f * xb.y + theta[5]));
        uq[3] = f2bf_pk(__cosf(2.f * xb.z + theta[6]), __cosf(2.f * xb.w + theta[7]));
        qfrag[mh] = __builtin_bit_cast(short8, uq);
        if (hi) qfrag[mh] = (short8)0;
    }

    // ---- per-thread B-staging constants (chunk -> source-swizzled gaddr) ----
    // B tile = BN*4 = 1024 chunks of 16 B; 256 threads -> 4 chunks each.
    const unsigned short* gB[4];
#pragma unroll
    for (int i = 0; i < 4; ++i) {
        int c = i * NTHREADS + t;
        int n = c >> 2, s = c & 3;
        gB[i] = w2b + (size_t)(n0 + n) * FFN + (s ^ ((n >> 1) & 3)) * 8;
    }

    auto stageB = [&](int k0, int buf) __attribute__((always_inline)) {
#pragma unroll
        for (int i = 0; i < 4; ++i) {
            int c = i * NTHREADS + t;
            __builtin_amdgcn_global_load_lds(
                (const __attribute__((address_space(1))) unsigned int*)(gB[i] + k0),
                (__attribute__((address_space(3))) unsigned int*)(uintptr_t)(&Bsm[buf][c * 8]),
                16, 0, 0);
        }
    };

    // W1 A-frag for f-rows [k, k+32): lane row = l32, k-slot hi*8+j.
    // hi=0: 16 B from permuted w1p; hi=1 (k=8..15): zero.
    auto loadW1 = [&](int k) __attribute__((always_inline)) -> short8 {
        short8 w = (short8)0;
        if (hi == 0) w = *(const short8*)&w1p[(size_t)(k + l32) * NQ];
        return w;
    };

    float16v acc[2][4];
#pragma unroll
    for (int mh = 0; mh < 2; ++mh)
#pragma unroll
        for (int nh = 0; nh < 4; ++nh) acc[mh][nh] = (float16v)0.0f;

    // h-gen: one 32x32x16 MFMA per m-subtile; relu + cvt_pk -> A-frags.
    // D slot s holds h[sigma(s)] (sigma baked into w1p), so dwords d0..d3 /
    // d4..d7 are exactly af(kk=0) / af(kk=1) for both lane halves.
    short8 af[2][2];   // [mh][kk]
    auto hgen = [&](short8 w1f) __attribute__((always_inline)) {
#pragma unroll
        for (int mh = 0; mh < 2; ++mh) {
            float16v hc = __builtin_amdgcn_mfma_f32_32x32x16_bf16(
                w1f, qfrag[mh], (float16v)0.0f, 0, 0, 0);
            unsigned int d[8];
#pragma unroll
            for (int r = 0; r < 8; ++r)
                d[r] = cvt_pk_bf16(fmaxf(hc[2 * r], 0.f), fmaxf(hc[2 * r + 1], 0.f));
            uint4v u0, u1;
            u0[0] = d[0]; u0[1] = d[1]; u0[2] = d[2]; u0[3] = d[3];
            u1[0] = d[4]; u1[1] = d[5]; u1[2] = d[6]; u1[3] = d[7];
            af[mh][0] = __builtin_bit_cast(short8, u0);
            af[mh][1] = __builtin_bit_cast(short8, u1);
        }
    };

    // main: per nh, 2 conflict-free bfr reads + 4 MFMA (2 mh x 2 kk)
    auto mainC = [&](int buf) __attribute__((always_inline)) {
        __builtin_amdgcn_s_setprio(1);
#pragma unroll
        for (int nh = 0; nh < 4; ++nh) {
            int row = wn * 128 + nh * 32 + l32;
            int sw  = (row >> 1) & 3;
            short8 b0 = *(const short8*)&Bsm[buf][row * BK + ((hi)     ^ sw) * 8];
            short8 b1 = *(const short8*)&Bsm[buf][row * BK + ((2 + hi) ^ sw) * 8];
#pragma unroll
            for (int mh = 0; mh < 2; ++mh) {
                acc[mh][nh] = __builtin_amdgcn_mfma_f32_32x32x16_bf16(
                    af[mh][0], b0, acc[mh][nh], 0, 0, 0);
                acc[mh][nh] = __builtin_amdgcn_mfma_f32_32x32x16_bf16(
                    af[mh][1], b1, acc[mh][nh], 0, 0, 0);
            }
        }
        __builtin_amdgcn_s_setprio(0);
    };

    // ---- prologue ----
    short8 wA = loadW1(0), wB;
    stageB(0, 0);
    __syncthreads();        // B(0) landed (vmcnt drained by syncthreads)

    // ---- main loop: 64 K-steps, 1 barrier each (guards Bsm only) ----
    for (int kt = 0; kt < 62; kt += 2) {
        wB = loadW1((kt + 1) * BK);
        stageB((kt + 1) * BK, 1);
        hgen(wA);
        mainC(0);
        __syncthreads();

        wA = loadW1((kt + 2) * BK);
        stageB((kt + 2) * BK, 0);
        hgen(wB);
        mainC(1);
        __syncthreads();
    }
    // kt = 62: stage last tile (63), compute 62
    wB = loadW1(63 * BK);
    stageB(63 * BK, 1);
    hgen(wA);
    mainC(0);
    __syncthreads();
    // kt = 63: tail
    hgen(wB);
    mainC(1);

    // ---- epilogue: 32x32 D layout col=lane&31 (n), row=(r&3)+8*(r>>2)+4*hi ----
#pragma unroll
    for (int mh = 0; mh < 2; ++mh) {
#pragma unroll
        for (int nh = 0; nh < 4; ++nh) {
            float16v v = acc[mh][nh];
            int n  = n0 + wn * 128 + nh * 32 + l32;
            int mb = m0 + wm * 64 + mh * 32 + 4 * hi;
#pragma unroll
            for (int r = 0; r < 16; ++r) {
                int m = mb + (r & 3) + 8 * (r >> 2);
                out[(size_t)m * EMB + n] = v[r];
            }
        }
    }
}

extern "C" void kernel_launch(void* const* d_in, const int* in_sizes, int n_in,
                              void* d_out, int out_size, void* d_ws, size_t ws_size,
                              hipStream_t stream) {
    const float* x     = (const float*)d_in[0];
    const float* theta = (const float*)d_in[1];
    const float* W1    = (const float*)d_in[2];
    const float* W2    = (const float*)d_in[3];
    float* out = (float*)d_out;

    unsigned int* w2b = (unsigned int*)d_ws;               // 2 MiB (bf16 bits)
    unsigned int* w1p = (unsigned int*)((char*)d_ws + (size_t)EMB * FFN * 2);  // 32 KB

    prep_w2<<<(EMB * FFN) / (256 * 4), 256, 0, stream>>>(W2, w2b);
    prep_w1<<<FFN / 256, 256, 0, stream>>>(W1, w1p);       // 8 blocks

    dim3 grid(M_TOTAL / BM, EMB / BN);         // 256 x 2 = 512 blocks, 2/CU
    ffq_main<<<grid, NTHREADS, 0, stream>>>(x, theta,
                                            (const unsigned short*)w1p,
                                            (const unsigned short*)w2b, out);
}